// Round 1
// baseline (84.245 us; speedup 1.0000x reference)
//
#include <hip/hip_runtime.h>

// E[b] = sum_p decompFE_flat[b,p] / r(b, pair p), pairs = strict lower tri row-major.
// B=2048, N=100, NC2=4950.
//
// R2 changes vs R1 (theory: decomp stream was scalar 4B/lane ~2.7 TB/s + 20 extra
// ushort table loads per thread):
//  - float2 (8B/lane) decomp loads, 2 consecutive pairs per thread-group.
//    (rows are 19800 B -> 8B-aligned for all b; 16B is not, so float2 not float4)
//  - pair indices computed arithmetically: i = floor((1+sqrt(8p+1))/2), j = p - i(i-1)/2.
//    Exact in fp32 for p < 4950; +0.5 inside sqrt guards against ULP-low sqrt.
//  - coords LDS layout derotated: atom j at slot (j&1)*64 + j/2 so stride-2 same-parity
//    j access (consecutive lanes) stays slot-dense -> ds_read_b128 remains 8-phase optimal.

#define BATCH 2048
#define NATOMS 100
#define NPAIRS 4950
#define NGROUPS (NPAIRS / 2)   // 2475 float2 groups per batch
#define BLOCK 256
#define KMAX 10                // ceil(2475/256)

typedef float v2f __attribute__((ext_vector_type(2)));

__global__ __launch_bounds__(BLOCK) void eij_kernel(
    const float* __restrict__ coords,   // [B, N, 3]
    const float* __restrict__ decomp,   // [B, NC2]
    float* __restrict__ out)            // [B, 1]
{
    // Atom j lives at slot m(j) = (j&1)*64 + j/2 (slots 0..113, padded to 128).
    __shared__ float4 satom[128];
    __shared__ float wave_sums[BLOCK / 64];

    const int b = blockIdx.x;
    const int t = threadIdx.x;

    const float* cb = coords + (size_t)b * (NATOMS * 3);
    if (t < NATOMS) {
        const int slot = ((t & 1) << 6) | (t >> 1);
        satom[slot] = make_float4(cb[t * 3 + 0], cb[t * 3 + 1], cb[t * 3 + 2], 0.0f);
    }
    __syncthreads();

    // 8-byte aligned for every b: b*4950 floats = b*19800 bytes, 19800 % 8 == 0.
    const v2f* db2 = (const v2f*)(decomp + (size_t)b * NPAIRS);
    float acc = 0.0f;

    #pragma unroll
    for (int k = 0; k < KMAX; ++k) {
        const int g = t + (k << 8);
        const bool ok = (g < NGROUPS);      // only k==9 is ragged
        const int gg = ok ? g : 0;          // clamp: load stays unconditional
        const v2f d = db2[gg];              // global_load_dwordx2, coalesced 8B/lane

        // First pair of the group: p0 = 2*gg.
        // i0 = floor((1+sqrt(8*p0+1))/2); guard +0.5 keeps the floor safe vs sqrt ULP:
        //   lower edge p=tri(i): sqrt((2i-1)^2+0.5) in (2i-1, 2i-1+0.25] -> floor i. ok
        //   upper edge p=tri(i+1)-1: sqrt((2i+1)^2-7.5) < 2i+1 -> floor i. ok
        const float gf = (float)gg;
        const float s  = sqrtf(__builtin_fmaf(16.0f, gf, 1.5f));  // sqrt(8*p0 + 1.5)
        const int   i0 = (int)(0.5f * (1.0f + s));                // trunc == floor (>0)
        const int   p0 = gg << 1;
        const int   j0 = p0 - ((i0 * (i0 - 1)) >> 1);

        // Second pair: row-major increment with row-wrap.
        const bool wrap = (j0 + 1 == i0);
        const int  i1   = i0 + (wrap ? 1 : 0);
        const int  j1   = wrap ? 0 : (j0 + 1);

        const float4 ci0 = satom[((i0 & 1) << 6) | (i0 >> 1)];   // broadcast (row-run)
        const float4 cj0 = satom[((j0 & 1) << 6) | (j0 >> 1)];   // slot-dense
        const float4 ci1 = satom[((i1 & 1) << 6) | (i1 >> 1)];
        const float4 cj1 = satom[((j1 & 1) << 6) | (j1 >> 1)];

        const float dx0 = ci0.x - cj0.x, dy0 = ci0.y - cj0.y, dz0 = ci0.z - cj0.z;
        const float dx1 = ci1.x - cj1.x, dy1 = ci1.y - cj1.y, dz1 = ci1.z - cj1.z;
        const float r20 = dx0 * dx0 + dy0 * dy0 + dz0 * dz0;
        const float r21 = dx1 * dx1 + dy1 * dy1 + dz1 * dz1;

        const float c = d[0] * rsqrtf(r20) + d[1] * rsqrtf(r21);
        acc += ok ? c : 0.0f;
    }

    // Wave-64 shuffle reduction, then cross-wave via LDS.
    #pragma unroll
    for (int off = 32; off > 0; off >>= 1)
        acc += __shfl_down(acc, off, 64);

    if ((t & 63) == 0) wave_sums[t >> 6] = acc;
    __syncthreads();

    if (t == 0)
        out[b] = wave_sums[0] + wave_sums[1] + wave_sums[2] + wave_sums[3];
}

extern "C" void kernel_launch(void* const* d_in, const int* in_sizes, int n_in,
                              void* d_out, int out_size, void* d_ws, size_t ws_size,
                              hipStream_t stream) {
    const float* coords = (const float*)d_in[0];   // [2048, 100, 3]
    const float* decomp = (const float*)d_in[1];   // [2048, 4950]
    float* out = (float*)d_out;                    // [2048, 1]

    eij_kernel<<<BATCH, BLOCK, 0, stream>>>(coords, decomp, out);
}